// Round 1
// baseline (1753.528 us; speedup 1.0000x reference)
//
#include <hip/hip_runtime.h>

// ---------------------------------------------------------------------------
// FocusAttention fused pipeline for MI355X (gfx950)
// B=4, C=256, H=W=256, ws=4, heads=8, d=32
//
// Pipeline:
//   k_prep     : fold BNs into weights/biases, bf16-cast weights, expand rel bias
//   k_qkv_attn : fused qkv GEMM + window attention -> attn_img(bf16), v_img(bf16)
//   k_pw       : vg = gaze_pw @ v_img (bf16 GEMM)
//   k_mix      : t = v_img + BN(dw3x3(vg)) + ax + ay   (pool semantics exact)
//   k_proj     : out = BNfold(proj_w) @ t + bias  (fp32 out; pad+crop is identity)
//
// R0 FIX: Phase-C PV B-frag reads touch Vs padding cols (64..71) and (for
// c=255) spill into Ps. Those LDS bytes were previously UNINITIALIZED; if the
// stale bits decode as NaN/Inf, 0*NaN=NaN poisons the accumulator (observed
// harness NaN). Now zero-filled in Phase A before any barrier.
//
// Workspace layout (bytes):
//   [0)        Wqkv bf16   768*256*2 = 393216
//   [393216)   Wpw  bf16   256*256*2 = 131072
//   [524288)   Wproj bf16  131072
//   [655360)   bqkv f32    3072
//   [658432)   biasT f32   8*16*16*4 = 8192      (rel bias as [h][i][j])
//   [666624)   dwf  f32    256*9*4 = 9216        (dw weights * bn scale)
//   [675840)   bias_g f32  1024
//   [676864)   bias_p f32  1024
//   [1MB)      attn_img bf16 128MB
//   [1MB+128M) v_img    bf16 128MB
//   [1MB+256M) vg       bf16 128MB
//   [1MB+384M) t        bf16 128MB     -> total ~513MB of d_ws
// ---------------------------------------------------------------------------

typedef float  f32x4  __attribute__((ext_vector_type(4)));
typedef __bf16 bf16x8 __attribute__((ext_vector_type(8)));
typedef __bf16 bf16x4 __attribute__((ext_vector_type(4)));

#define HW 65536
#define EPSF 1e-5f

// ---------------------------------------------------------------- prep ------
__global__ __launch_bounds__(256) void k_prep(
    const float* __restrict__ qkv_w, const float* __restrict__ qkv_b,
    const float* __restrict__ rel_tab,
    const float* __restrict__ gaze_pw, const float* __restrict__ gaze_dw,
    const float* __restrict__ g_g, const float* __restrict__ g_b,
    const float* __restrict__ g_m, const float* __restrict__ g_v,
    const float* __restrict__ proj_w,
    const float* __restrict__ p_g, const float* __restrict__ p_b,
    const float* __restrict__ p_m, const float* __restrict__ p_v,
    __bf16* Wqkv, __bf16* Wpw, __bf16* Wproj,
    float* bqkv, float* biasT, float* dwf, float* bias_g, float* bias_p)
{
  int i = blockIdx.x * 256 + threadIdx.x;
  if (i < 196608) { Wqkv[i] = (__bf16)qkv_w[i]; return; }
  i -= 196608;
  if (i < 65536) { Wpw[i] = (__bf16)gaze_pw[i]; return; }
  i -= 65536;
  if (i < 65536) {
    int o = i >> 8;
    float s = p_g[o] * rsqrtf(p_v[o] + EPSF);
    Wproj[i] = (__bf16)(proj_w[i] * s);
    return;
  }
  i -= 65536;
  if (i < 768) { bqkv[i] = qkv_b[i]; return; }
  i -= 768;
  if (i < 2048) { // biasT[h][i][j]
    int h = i >> 8, q = (i >> 4) & 15, k = i & 15;
    int rel = ((q >> 2) - (k >> 2) + 3) * 7 + ((q & 3) - (k & 3) + 3);
    biasT[i] = rel_tab[rel * 8 + h];
    return;
  }
  i -= 2048;
  if (i < 2304) {
    int c = i / 9;
    float s = g_g[c] * rsqrtf(g_v[c] + EPSF);
    dwf[i] = gaze_dw[i] * s;
    return;
  }
  i -= 2304;
  if (i < 256) {
    float s = g_g[i] * rsqrtf(g_v[i] + EPSF);
    bias_g[i] = g_b[i] - g_m[i] * s;
    return;
  }
  i -= 256;
  if (i < 256) {
    float s = p_g[i] * rsqrtf(p_v[i] + EPSF);
    bias_p[i] = p_b[i] - p_m[i] * s;
    return;
  }
}

// ---------------------------------------------------- fused qkv + attention --
// Block: 512 thr (8 waves). Tile: 4 rows x 16 cols = 64 px = 4 windows.
// LDS (dynamic, 145408B):
//   Xs  [64][264]  bf16  x^T tile           (33792B)
//   QKs [64][520]  bf16  q(0..255)|k(256..511) per token   (66560B)
//   Vs  [256][72]  bf16  v^T  [chan][token]  (36864B)
//   Ps  [8][16][32] bf16 per-wave softmax probs, j>=16 zeroed (8192B)
//   Os = reuse of QKs for attn output staging [256][72]
#define K2_SMEM 145408

__global__ __launch_bounds__(512, 2) void k_qkv_attn(
    const float* __restrict__ x, const __bf16* __restrict__ Wqkv,
    const float* __restrict__ bqkv, const float* __restrict__ biasT,
    __bf16* __restrict__ attn_img, __bf16* __restrict__ v_img)
{
  extern __shared__ char smem[];
  __bf16* Xs  = (__bf16*)smem;          // 64*264
  __bf16* QKs = Xs + 64 * 264;          // 64*520
  __bf16* Vs  = QKs + 64 * 520;         // 256*72
  __bf16* Ps  = Vs + 256 * 72;          // 8*512
  __bf16* Os  = QKs;                    // reuse

  const int tid  = threadIdx.x;
  const int lane = tid & 63, wid = tid >> 6;
  const int mrow = lane & 15, kgrp = lane >> 4;
  const int b = blockIdx.z, h0 = blockIdx.y * 4, w0 = blockIdx.x * 16;

  // ---- Phase A0: zero the LDS bytes that Phase-C stray B-frag reads touch.
  // Vs padding cols 64..71 of all 256 rows (2048 elems) + entire Ps (4096
  // elems). Ordered before Phase-C reads by the Phase A/B barriers.
  {
    bf16x4 z4;
    z4[0] = z4[1] = z4[2] = z4[3] = (__bf16)0.f;
    *(bf16x4*)(Vs + (tid >> 1) * 72 + 64 + (tid & 1) * 4) = z4;   // 512 thr
    bf16x8 z8;
#pragma unroll
    for (int j = 0; j < 8; ++j) z8[j] = (__bf16)0.f;
    *(bf16x8*)(Ps + tid * 8) = z8;                                 // 512*8=4096
  }

  // ---- Phase A: stage x^T tile (fp32 -> bf16 transpose) ----
  const float* xb = x + (size_t)b * 256 * HW + (size_t)h0 * 256 + w0;
#pragma unroll
  for (int it = 0; it < 8; ++it) {
    int idx = tid + it * 512;            // 0..4095 = c(256) x r(4) x g(4)
    int c = idx >> 4, r = (idx >> 2) & 3, g = idx & 3;
    f32x4 v = *(const f32x4*)(xb + (size_t)c * HW + r * 256 + g * 4);
    int p = r * 16 + g * 4;
    Xs[(p + 0) * 264 + c] = (__bf16)v[0];
    Xs[(p + 1) * 264 + c] = (__bf16)v[1];
    Xs[(p + 2) * 264 + c] = (__bf16)v[2];
    Xs[(p + 3) * 264 + c] = (__bf16)v[3];
  }
  __syncthreads();

  // ---- Phase B: qkv GEMM, 6 chunks of 128 out-channels ----
  for (int co = 0; co < 6; ++co) {
    f32x4 acc[4] = {{0.f,0.f,0.f,0.f},{0.f,0.f,0.f,0.f},
                    {0.f,0.f,0.f,0.f},{0.f,0.f,0.f,0.f}};
    const int ob = co * 128 + wid * 16;   // this wave's o-strip base
    const __bf16* wp = Wqkv + (size_t)(ob + mrow) * 256 + kgrp * 8;
#pragma unroll
    for (int ks = 0; ks < 8; ++ks) {
      bf16x8 af = *(const bf16x8*)(wp + ks * 32);       // A: W rows (L2)
#pragma unroll
      for (int j = 0; j < 4; ++j) {
        bf16x8 bm = *(const bf16x8*)(Xs + (j * 16 + mrow) * 264 + ks * 32 + kgrp * 8);
        acc[j] = __builtin_amdgcn_mfma_f32_16x16x32_bf16(af, bm, acc[j], 0, 0, 0);
      }
    }
    f32x4 bi = *(const f32x4*)(bqkv + ob + kgrp * 4);
    if (co < 4) { // q (scaled by d^-0.5) or k -> QKs[token][chan]
      float sc = (co < 2) ? 0.17677669529663687f : 1.0f;
#pragma unroll
      for (int j = 0; j < 4; ++j) {
        int p = j * 16 + mrow;
        bf16x4 pk;
#pragma unroll
        for (int t = 0; t < 4; ++t) pk[t] = (__bf16)((acc[j][t] + bi[t]) * sc);
        *(bf16x4*)(QKs + p * 520 + ob + kgrp * 4) = pk;
      }
    } else {      // v -> Vs[chan][token]
      int cb = ob - 512 + kgrp * 4;
#pragma unroll
      for (int j = 0; j < 4; ++j) {
        int p = j * 16 + mrow;
#pragma unroll
        for (int t = 0; t < 4; ++t)
          Vs[(cb + t) * 72 + p] = (__bf16)(acc[j][t] + bi[t]);
      }
    }
  }
  __syncthreads();

  // ---- Phase C: window attention (4 window-heads per wave) ----
  bf16x4 osav[4][2];
#pragma unroll
  for (int u = 0; u < 4; ++u) {
    int wh = wid * 4 + u;
    int win = wh >> 3, head = wh & 7;
    int ptok = (mrow >> 2) * 16 + win * 4 + (mrow & 3);   // token -> tile pixel
    bf16x8 kf = *(const bf16x8*)(QKs + ptok * 520 + 256 + head * 32 + kgrp * 8);
    bf16x8 qf = *(const bf16x8*)(QKs + ptok * 520 + head * 32 + kgrp * 8);
    f32x4 z4 = {0.f, 0.f, 0.f, 0.f};
    // D = dots^T: lane holds col i = mrow, rows j = kgrp*4+t
    f32x4 d = __builtin_amdgcn_mfma_f32_16x16x32_bf16(kf, qf, z4, 0, 0, 0);
    f32x4 bt = *(const f32x4*)(biasT + head * 256 + mrow * 16 + kgrp * 4);
    float s0 = d[0] + bt[0], s1 = d[1] + bt[1], s2 = d[2] + bt[2], s3 = d[3] + bt[3];
    float mx = fmaxf(fmaxf(s0, s1), fmaxf(s2, s3));
    mx = fmaxf(mx, __shfl_xor(mx, 16));
    mx = fmaxf(mx, __shfl_xor(mx, 32));
    float e0 = __expf(s0 - mx), e1 = __expf(s1 - mx);
    float e2 = __expf(s2 - mx), e3 = __expf(s3 - mx);
    float sm = e0 + e1 + e2 + e3;
    sm += __shfl_xor(sm, 16);
    sm += __shfl_xor(sm, 32);
    float inv = 1.0f / sm;
    bf16x4 pk;
    pk[0] = (__bf16)(e0 * inv); pk[1] = (__bf16)(e1 * inv);
    pk[2] = (__bf16)(e2 * inv); pk[3] = (__bf16)(e3 * inv);
    *(bf16x4*)(Ps + wid * 512 + mrow * 32 + kgrp * 4) = pk;
    // A-frag: probs[i=mrow][j = kgrp*8..+7] (zeros for j>=16, zeroed in A0)
    bf16x8 pf = *(const bf16x8*)(Ps + wid * 512 + mrow * 32 + kgrp * 8);
#pragma unroll
    for (int dt = 0; dt < 2; ++dt) {
      int c = head * 32 + dt * 16 + mrow;
      // B-frag: v[j][d=mrow] for 8 consecutive j. Reads for j>=16 land in
      // Vs padding cols / Ps, which are ZEROED (Phase A0) -> 0*0=0, finite.
      bf16x4 va = *(const bf16x4*)(Vs + c * 72 + kgrp * 32 + win * 4);
      bf16x4 vb = *(const bf16x4*)(Vs + c * 72 + kgrp * 32 + 16 + win * 4);
      bf16x8 vf;
#pragma unroll
      for (int t = 0; t < 4; ++t) { vf[t] = va[t]; vf[4 + t] = vb[t]; }
      f32x4 o = __builtin_amdgcn_mfma_f32_16x16x32_bf16(pf, vf, z4, 0, 0, 0);
      bf16x4 ok;
#pragma unroll
      for (int t = 0; t < 4; ++t) ok[t] = (__bf16)o[t];
      osav[u][dt] = ok;
    }
  }
  __syncthreads();   // all QKs reads done -> safe to overwrite with Os
#pragma unroll
  for (int u = 0; u < 4; ++u) {
    int wh = wid * 4 + u, win = wh >> 3, head = wh & 7;
#pragma unroll
    for (int dt = 0; dt < 2; ++dt) {
      int c = head * 32 + dt * 16 + mrow;
      *(bf16x4*)(Os + c * 72 + kgrp * 16 + win * 4) = osav[u][dt];
    }
  }
  __syncthreads();

  // ---- writeout: attn_img from Os, v_img from Vs (coalesced 16B) ----
#pragma unroll
  for (int it = 0; it < 4; ++it) {
    int idx = tid + it * 512;            // 2048 = c(256) x seg(8)
    int c = idx >> 3, seg = idx & 7;
    bf16x8 o8 = *(const bf16x8*)(Os + c * 72 + seg * 8);
    bf16x8 v8 = *(const bf16x8*)(Vs + c * 72 + seg * 8);
    size_t g = ((size_t)(b * 256 + c) * 256 + h0 + (seg >> 1)) * 256 + w0 + (seg & 1) * 8;
    *(bf16x8*)(attn_img + g) = o8;
    *(bf16x8*)(v_img + g) = v8;
  }
}

// ------------------------------------------------------------ pw GEMM -------
// Block 256 thr (4 waves), tile = 64 contiguous w of one row. M=256 in 2 chunks.
__global__ __launch_bounds__(256, 4) void k_pw(
    const __bf16* __restrict__ vimg, const __bf16* __restrict__ Wpw,
    __bf16* __restrict__ vg)
{
  __shared__ __bf16 Xs[64 * 264];
  const int tid = threadIdx.x, lane = tid & 63, wid = tid >> 6;
  const int mrow = lane & 15, kgrp = lane >> 4;
  const int b = blockIdx.z, h = blockIdx.y, w0 = blockIdx.x * 64;
  const size_t rowbase = ((size_t)(b * 256) * 256 + h) * 256 + w0;
#pragma unroll
  for (int it = 0; it < 8; ++it) {
    int idx = tid + it * 256;            // c(256) x g(8)
    int c = idx >> 3, g = idx & 7;
    bf16x8 v = *(const bf16x8*)(vimg + rowbase + (size_t)c * HW + g * 8);
#pragma unroll
    for (int j = 0; j < 8; ++j) Xs[(g * 8 + j) * 264 + c] = v[j];
  }
  __syncthreads();
  for (int oh = 0; oh < 2; ++oh) {
    int o0 = oh * 128 + wid * 32;
    f32x4 acc[2][4];
#pragma unroll
    for (int mt = 0; mt < 2; ++mt)
#pragma unroll
      for (int nt = 0; nt < 4; ++nt) acc[mt][nt] = (f32x4){0.f, 0.f, 0.f, 0.f};
#pragma unroll
    for (int ks = 0; ks < 8; ++ks) {
      bf16x8 af[2], bm[4];
#pragma unroll
      for (int mt = 0; mt < 2; ++mt)
        af[mt] = *(const bf16x8*)(Wpw + (size_t)(o0 + mt * 16 + mrow) * 256 + ks * 32 + kgrp * 8);
#pragma unroll
      for (int nt = 0; nt < 4; ++nt)
        bm[nt] = *(const bf16x8*)(Xs + (nt * 16 + mrow) * 264 + ks * 32 + kgrp * 8);
#pragma unroll
      for (int mt = 0; mt < 2; ++mt)
#pragma unroll
        for (int nt = 0; nt < 4; ++nt)
          acc[mt][nt] = __builtin_amdgcn_mfma_f32_16x16x32_bf16(af[mt], bm[nt], acc[mt][nt], 0, 0, 0);
    }
#pragma unroll
    for (int mt = 0; mt < 2; ++mt)
#pragma unroll
      for (int nt = 0; nt < 4; ++nt)
#pragma unroll
        for (int t = 0; t < 4; ++t) {
          int o = o0 + mt * 16 + kgrp * 4 + t;
          int p = nt * 16 + mrow;
          vg[rowbase + (size_t)o * HW + p] = (__bf16)acc[mt][nt][t];
        }
  }
}

// ------------------------------------------------------------- mix ----------
// t = v_img + (dw3x3(vg)*s_g + bias_g) + ax + ay
// ax[h] = (A~[h-1]+A~[h]+A~[h+1]+A~[h+2])/4, A~[256]=A[254], A~[-1]=A~[257]=0
// ay analogous along w.
__global__ __launch_bounds__(256, 4) void k_mix(
    const __bf16* __restrict__ vg, const __bf16* __restrict__ attn,
    const __bf16* __restrict__ vimg, const float* __restrict__ dwf,
    const float* __restrict__ bias_g, __bf16* __restrict__ tout)
{
  __shared__ __bf16 VgS[18 * 256];
  __shared__ __bf16 AtS[19 * 256];
  __shared__ __bf16 ViS[16 * 256];
  const int tid = threadIdx.x;
  const int b = blockIdx.z, c = blockIdx.y, h0 = blockIdx.x * 16;
  const size_t plane = (size_t)(b * 256 + c) * HW;

  for (int idx = tid; idx < 576; idx += 256) {        // vg rows h0-1..h0+16
    int row = idx >> 5, g = idx & 31;
    int hg = h0 - 1 + row;
    bf16x8 v;
#pragma unroll
    for (int j = 0; j < 8; ++j) v[j] = (__bf16)0.f;
    if (hg >= 0 && hg < 256)
      v = *(const bf16x8*)(vg + plane + (size_t)hg * 256 + g * 8);
    *(bf16x8*)(VgS + row * 256 + g * 8) = v;
  }
  for (int idx = tid; idx < 608; idx += 256) {        // attn rows h0-1..h0+17
    int row = idx >> 5, g = idx & 31;
    int hg = h0 - 1 + row;
    bf16x8 v;
#pragma unroll
    for (int j = 0; j < 8; ++j) v[j] = (__bf16)0.f;
    if (hg >= 0 && hg <= 256) {
      int hs = (hg == 256) ? 254 : hg;                // reflect-appended row
      v = *(const bf16x8*)(attn + plane + (size_t)hs * 256 + g * 8);
    }
    *(bf16x8*)(AtS + row * 256 + g * 8) = v;
  }
  for (int idx = tid; idx < 512; idx += 256) {        // v_img rows h0..h0+15
    int row = idx >> 5, g = idx & 31;
    *(bf16x8*)(ViS + row * 256 + g * 8) =
        *(const bf16x8*)(vimg + plane + (size_t)(h0 + row) * 256 + g * 8);
  }
  float kw[9];
#pragma unroll
  for (int i = 0; i < 9; ++i) kw[i] = dwf[c * 9 + i];
  const float bg = bias_g[c];
  __syncthreads();

  const int hl = tid >> 4, wb = (tid & 15) * 16;
  const __bf16* v0 = VgS + hl * 256;
  const __bf16* v1 = v0 + 256;
  const __bf16* v2 = v1 + 256;
  const __bf16* a0 = AtS + hl * 256;
  const __bf16* a1 = a0 + 256;
  const __bf16* a2 = a1 + 256;
  const __bf16* a3 = a2 + 256;
  const __bf16* vi = ViS + hl * 256;
  const size_t orow = plane + (size_t)(h0 + hl) * 256;
  for (int w8 = 0; w8 < 2; ++w8) {
    bf16x8 res;
#pragma unroll
    for (int j = 0; j < 8; ++j) {
      int w = wb + w8 * 8 + j;
      int xm = w - 1, xp = w + 1;
      float conv = kw[1] * (float)v0[w] + kw[4] * (float)v1[w] + kw[7] * (float)v2[w];
      if (xm >= 0)
        conv += kw[0] * (float)v0[xm] + kw[3] * (float)v1[xm] + kw[6] * (float)v2[xm];
      if (xp < 256)
        conv += kw[2] * (float)v0[xp] + kw[5] * (float)v1[xp] + kw[8] * (float)v2[xp];
      float ax = 0.25f * ((float)a0[w] + (float)a1[w] + (float)a2[w] + (float)a3[w]);
      float aym = (w >= 1) ? (float)a1[w - 1] : 0.f;
      float ay1 = (w + 1 <= 255) ? (float)a1[w + 1] : (float)a1[254];
      float ay2;
      int x2 = w + 2;
      if (x2 <= 255) ay2 = (float)a1[x2];
      else if (x2 == 256) ay2 = (float)a1[254];
      else ay2 = 0.f;
      float ay = 0.25f * (aym + (float)a1[w] + ay1 + ay2);
      res[j] = (__bf16)((float)vi[w] + conv + bg + ax + ay);
    }
    *(bf16x8*)(tout + orow + wb + w8 * 8) = res;
  }
}

// ------------------------------------------------------------ proj GEMM -----
__global__ __launch_bounds__(256, 4) void k_proj(
    const __bf16* __restrict__ tin, const __bf16* __restrict__ Wp,
    const float* __restrict__ bias_p, float* __restrict__ out)
{
  __shared__ __bf16 Xs[64 * 264];
  const int tid = threadIdx.x, lane = tid & 63, wid = tid >> 6;
  const int mrow = lane & 15, kgrp = lane >> 4;
  const int b = blockIdx.z, h = blockIdx.y, w0 = blockIdx.x * 64;
  const size_t rowbase = ((size_t)(b * 256) * 256 + h) * 256 + w0;
#pragma unroll
  for (int it = 0; it < 8; ++it) {
    int idx = tid + it * 256;
    int c = idx >> 3, g = idx & 7;
    bf16x8 v = *(const bf16x8*)(tin + rowbase + (size_t)c * HW + g * 8);
#pragma unroll
    for (int j = 0; j < 8; ++j) Xs[(g * 8 + j) * 264 + c] = v[j];
  }
  __syncthreads();
  for (int oh = 0; oh < 2; ++oh) {
    int o0 = oh * 128 + wid * 32;
    f32x4 acc[2][4];
#pragma unroll
    for (int mt = 0; mt < 2; ++mt)
#pragma unroll
      for (int nt = 0; nt < 4; ++nt) acc[mt][nt] = (f32x4){0.f, 0.f, 0.f, 0.f};
#pragma unroll
    for (int ks = 0; ks < 8; ++ks) {
      bf16x8 af[2], bm[4];
#pragma unroll
      for (int mt = 0; mt < 2; ++mt)
        af[mt] = *(const bf16x8*)(Wp + (size_t)(o0 + mt * 16 + mrow) * 256 + ks * 32 + kgrp * 8);
#pragma unroll
      for (int nt = 0; nt < 4; ++nt)
        bm[nt] = *(const bf16x8*)(Xs + (nt * 16 + mrow) * 264 + ks * 32 + kgrp * 8);
#pragma unroll
      for (int mt = 0; mt < 2; ++mt)
#pragma unroll
        for (int nt = 0; nt < 4; ++nt)
          acc[mt][nt] = __builtin_amdgcn_mfma_f32_16x16x32_bf16(af[mt], bm[nt], acc[mt][nt], 0, 0, 0);
    }
#pragma unroll
    for (int mt = 0; mt < 2; ++mt) {
      f32x4 bi = *(const f32x4*)(bias_p + o0 + mt * 16 + kgrp * 4);
#pragma unroll
      for (int nt = 0; nt < 4; ++nt)
#pragma unroll
        for (int t = 0; t < 4; ++t) {
          int o = o0 + mt * 16 + kgrp * 4 + t;
          int p = nt * 16 + mrow;
          out[rowbase + (size_t)o * HW + p] = acc[mt][nt][t] + bi[t];
        }
    }
  }
}

// ----------------------------------------------------------- launcher -------
extern "C" void kernel_launch(void* const* d_in, const int* in_sizes, int n_in,
                              void* d_out, int out_size, void* d_ws, size_t ws_size,
                              hipStream_t stream) {
  const float* x      = (const float*)d_in[0];
  const float* qkv_w  = (const float*)d_in[1];
  const float* qkv_b  = (const float*)d_in[2];
  const float* rel    = (const float*)d_in[3];
  const float* gpw    = (const float*)d_in[4];
  const float* gdw    = (const float*)d_in[5];
  const float* gg     = (const float*)d_in[6];
  const float* gb     = (const float*)d_in[7];
  const float* gm     = (const float*)d_in[8];
  const float* gv     = (const float*)d_in[9];
  const float* pw     = (const float*)d_in[10];
  const float* pg     = (const float*)d_in[11];
  const float* pb     = (const float*)d_in[12];
  const float* pm     = (const float*)d_in[13];
  const float* pv     = (const float*)d_in[14];

  char* ws = (char*)d_ws;
  __bf16* Wqkv   = (__bf16*)(ws + 0);
  __bf16* Wpw    = (__bf16*)(ws + 393216);
  __bf16* Wproj  = (__bf16*)(ws + 524288);
  float*  bqkv   = (float*)(ws + 655360);
  float*  biasT  = (float*)(ws + 658432);
  float*  dwf    = (float*)(ws + 666624);
  float*  bias_g = (float*)(ws + 675840);
  float*  bias_p = (float*)(ws + 676864);
  __bf16* attn_img = (__bf16*)(ws + (1 << 20));
  __bf16* v_img    = attn_img + 67108864;
  __bf16* vg       = v_img + 67108864;
  __bf16* tbuf     = vg + 67108864;
  float* out = (float*)d_out;

  // allow 145KB dynamic LDS on gfx950 (ignore failure; harmless if no-op)
  (void)hipFuncSetAttribute((const void*)k_qkv_attn,
                            hipFuncAttributeMaxDynamicSharedMemorySize, K2_SMEM);

  k_prep<<<1302, 256, 0, stream>>>(qkv_w, qkv_b, rel, gpw, gdw, gg, gb, gm, gv,
                                   pw, pg, pb, pm, pv,
                                   Wqkv, Wpw, Wproj, bqkv, biasT, dwf, bias_g, bias_p);

  dim3 g2(16, 64, 4);
  k_qkv_attn<<<g2, 512, K2_SMEM, stream>>>(x, Wqkv, bqkv, biasT, attn_img, v_img);

  dim3 g3(4, 256, 4);
  k_pw<<<g3, 256, 0, stream>>>(v_img, Wpw, vg);

  dim3 g4(16, 256, 4);
  k_mix<<<g4, 256, 0, stream>>>(vg, attn_img, v_img, dwf, bias_g, tbuf);

  k_proj<<<g3, 256, 0, stream>>>(tbuf, Wproj, bias_p, out);
}

// Round 2
// 1462.560 us; speedup vs baseline: 1.1989x; 1.1989x over previous
//
#include <hip/hip_runtime.h>

// ---------------------------------------------------------------------------
// FocusAttention fused pipeline for MI355X (gfx950)
// B=4, C=256, H=W=256, ws=4, heads=8, d=32
//
// Pipeline:
//   k_prep     : fold BNs into weights/biases, bf16-cast weights, expand rel bias
//   k_qkv_attn : fused qkv GEMM + window attention -> attn_img(bf16), v_img(bf16)
//   k_pw       : vg = gaze_pw @ v_img (bf16 GEMM)
//   k_mix      : t = v_img + BN(dw3x3(vg)) + ax + ay   (pool semantics exact)
//   k_proj     : out = BNfold(proj_w) @ t + bias  (fp32 out; pad+crop is identity)
//
// R1 changes (theory: LDS bank conflicts + scalar strided global stores):
//  - k_qkv_attn Phase A: remapped so simultaneous LDS writes have
//    lane-consecutive token index p -> bank = 4*col (2-way, free). Was 8-way.
//  - k_pw/k_proj: conflict-free double-bounce transpose staging (Ns natural ->
//    Xs transposed), K-chunked (2x128) to keep LDS at ~36KB (4 blocks/CU).
//  - k_pw/k_proj: MFMA operands SWAPPED -> D[px][o]; epilogue is vectorized
//    bf16x4/f32x4 stores (16/thread) instead of 64 scalar strided stores.
//
// Workspace layout (bytes): unchanged from R0.
// ---------------------------------------------------------------------------

typedef float  f32x4  __attribute__((ext_vector_type(4)));
typedef __bf16 bf16x8 __attribute__((ext_vector_type(8)));
typedef __bf16 bf16x4 __attribute__((ext_vector_type(4)));

#define HW 65536
#define EPSF 1e-5f

// ---------------------------------------------------------------- prep ------
__global__ __launch_bounds__(256) void k_prep(
    const float* __restrict__ qkv_w, const float* __restrict__ qkv_b,
    const float* __restrict__ rel_tab,
    const float* __restrict__ gaze_pw, const float* __restrict__ gaze_dw,
    const float* __restrict__ g_g, const float* __restrict__ g_b,
    const float* __restrict__ g_m, const float* __restrict__ g_v,
    const float* __restrict__ proj_w,
    const float* __restrict__ p_g, const float* __restrict__ p_b,
    const float* __restrict__ p_m, const float* __restrict__ p_v,
    __bf16* Wqkv, __bf16* Wpw, __bf16* Wproj,
    float* bqkv, float* biasT, float* dwf, float* bias_g, float* bias_p)
{
  int i = blockIdx.x * 256 + threadIdx.x;
  if (i < 196608) { Wqkv[i] = (__bf16)qkv_w[i]; return; }
  i -= 196608;
  if (i < 65536) { Wpw[i] = (__bf16)gaze_pw[i]; return; }
  i -= 65536;
  if (i < 65536) {
    int o = i >> 8;
    float s = p_g[o] * rsqrtf(p_v[o] + EPSF);
    Wproj[i] = (__bf16)(proj_w[i] * s);
    return;
  }
  i -= 65536;
  if (i < 768) { bqkv[i] = qkv_b[i]; return; }
  i -= 768;
  if (i < 2048) { // biasT[h][i][j]
    int h = i >> 8, q = (i >> 4) & 15, k = i & 15;
    int rel = ((q >> 2) - (k >> 2) + 3) * 7 + ((q & 3) - (k & 3) + 3);
    biasT[i] = rel_tab[rel * 8 + h];
    return;
  }
  i -= 2048;
  if (i < 2304) {
    int c = i / 9;
    float s = g_g[c] * rsqrtf(g_v[c] + EPSF);
    dwf[i] = gaze_dw[i] * s;
    return;
  }
  i -= 2304;
  if (i < 256) {
    float s = g_g[i] * rsqrtf(g_v[i] + EPSF);
    bias_g[i] = g_b[i] - g_m[i] * s;
    return;
  }
  i -= 256;
  if (i < 256) {
    float s = p_g[i] * rsqrtf(p_v[i] + EPSF);
    bias_p[i] = p_b[i] - p_m[i] * s;
    return;
  }
}

// ---------------------------------------------------- fused qkv + attention --
// Block: 512 thr (8 waves). Tile: 4 rows x 16 cols = 64 px = 4 windows.
// LDS (dynamic, 145408B):
//   Xs  [64][264]  bf16  x^T tile           (33792B)
//   QKs [64][520]  bf16  q(0..255)|k(256..511) per token   (66560B)
//   Vs  [256][72]  bf16  v^T  [chan][token]  (36864B)
//   Ps  [8][16][32] bf16 per-wave softmax probs, j>=16 zeroed (8192B)
//   Os = reuse of QKs for attn output staging [256][72]
#define K2_SMEM 145408

__global__ __launch_bounds__(512, 2) void k_qkv_attn(
    const float* __restrict__ x, const __bf16* __restrict__ Wqkv,
    const float* __restrict__ bqkv, const float* __restrict__ biasT,
    __bf16* __restrict__ attn_img, __bf16* __restrict__ v_img)
{
  extern __shared__ char smem[];
  __bf16* Xs  = (__bf16*)smem;          // 64*264
  __bf16* QKs = Xs + 64 * 264;          // 64*520
  __bf16* Vs  = QKs + 64 * 520;         // 256*72
  __bf16* Ps  = Vs + 256 * 72;          // 8*512
  __bf16* Os  = QKs;                    // reuse

  const int tid  = threadIdx.x;
  const int lane = tid & 63, wid = tid >> 6;
  const int mrow = lane & 15, kgrp = lane >> 4;
  const int b = blockIdx.z, h0 = blockIdx.y * 4, w0 = blockIdx.x * 16;

  // ---- Phase A0: zero the LDS bytes that Phase-C stray B-frag reads touch.
  {
    bf16x4 z4;
    z4[0] = z4[1] = z4[2] = z4[3] = (__bf16)0.f;
    *(bf16x4*)(Vs + (tid >> 1) * 72 + 64 + (tid & 1) * 4) = z4;   // 512 thr
    bf16x8 z8;
#pragma unroll
    for (int j = 0; j < 8; ++j) z8[j] = (__bf16)0.f;
    *(bf16x8*)(Ps + tid * 8) = z8;                                 // 512*8=4096
  }

  // ---- Phase A: stage x^T tile (fp32 -> bf16 transpose) ----
  // R1: lanes carry consecutive col (and thus consecutive token p per write
  // step) -> bank = 4*col mod 32 spreads over 8 banks x2 lanes (free).
  // 4 scalar f32 loads/thread stay 64B-coalesced (16 lanes consecutive col).
  const float* xb = x + (size_t)b * 256 * HW + (size_t)h0 * 256 + w0;
#pragma unroll
  for (int it = 0; it < 8; ++it) {
    int idx = it * 512 + tid;            // c(256) x col(16)
    int c = idx >> 4, col = idx & 15;
    const float* px = xb + (size_t)c * HW + col;
#pragma unroll
    for (int r = 0; r < 4; ++r)
      Xs[(r * 16 + col) * 264 + c] = (__bf16)px[(size_t)r * 256];
  }
  __syncthreads();

  // ---- Phase B: qkv GEMM, 6 chunks of 128 out-channels ----
  for (int co = 0; co < 6; ++co) {
    f32x4 acc[4] = {{0.f,0.f,0.f,0.f},{0.f,0.f,0.f,0.f},
                    {0.f,0.f,0.f,0.f},{0.f,0.f,0.f,0.f}};
    const int ob = co * 128 + wid * 16;   // this wave's o-strip base
    const __bf16* wp = Wqkv + (size_t)(ob + mrow) * 256 + kgrp * 8;
#pragma unroll
    for (int ks = 0; ks < 8; ++ks) {
      bf16x8 af = *(const bf16x8*)(wp + ks * 32);       // A: W rows (L2)
#pragma unroll
      for (int j = 0; j < 4; ++j) {
        bf16x8 bm = *(const bf16x8*)(Xs + (j * 16 + mrow) * 264 + ks * 32 + kgrp * 8);
        acc[j] = __builtin_amdgcn_mfma_f32_16x16x32_bf16(af, bm, acc[j], 0, 0, 0);
      }
    }
    f32x4 bi = *(const f32x4*)(bqkv + ob + kgrp * 4);
    if (co < 4) { // q (scaled by d^-0.5) or k -> QKs[token][chan]
      float sc = (co < 2) ? 0.17677669529663687f : 1.0f;
#pragma unroll
      for (int j = 0; j < 4; ++j) {
        int p = j * 16 + mrow;
        bf16x4 pk;
#pragma unroll
        for (int t = 0; t < 4; ++t) pk[t] = (__bf16)((acc[j][t] + bi[t]) * sc);
        *(bf16x4*)(QKs + p * 520 + ob + kgrp * 4) = pk;
      }
    } else {      // v -> Vs[chan][token]
      int cb = ob - 512 + kgrp * 4;
#pragma unroll
      for (int j = 0; j < 4; ++j) {
        int p = j * 16 + mrow;
#pragma unroll
        for (int t = 0; t < 4; ++t)
          Vs[(cb + t) * 72 + p] = (__bf16)(acc[j][t] + bi[t]);
      }
    }
  }
  __syncthreads();

  // ---- Phase C: window attention (4 window-heads per wave) ----
  bf16x4 osav[4][2];
#pragma unroll
  for (int u = 0; u < 4; ++u) {
    int wh = wid * 4 + u;
    int win = wh >> 3, head = wh & 7;
    int ptok = (mrow >> 2) * 16 + win * 4 + (mrow & 3);   // token -> tile pixel
    bf16x8 kf = *(const bf16x8*)(QKs + ptok * 520 + 256 + head * 32 + kgrp * 8);
    bf16x8 qf = *(const bf16x8*)(QKs + ptok * 520 + head * 32 + kgrp * 8);
    f32x4 z4 = {0.f, 0.f, 0.f, 0.f};
    // D = dots^T: lane holds col i = mrow, rows j = kgrp*4+t
    f32x4 d = __builtin_amdgcn_mfma_f32_16x16x32_bf16(kf, qf, z4, 0, 0, 0);
    f32x4 bt = *(const f32x4*)(biasT + head * 256 + mrow * 16 + kgrp * 4);
    float s0 = d[0] + bt[0], s1 = d[1] + bt[1], s2 = d[2] + bt[2], s3 = d[3] + bt[3];
    float mx = fmaxf(fmaxf(s0, s1), fmaxf(s2, s3));
    mx = fmaxf(mx, __shfl_xor(mx, 16));
    mx = fmaxf(mx, __shfl_xor(mx, 32));
    float e0 = __expf(s0 - mx), e1 = __expf(s1 - mx);
    float e2 = __expf(s2 - mx), e3 = __expf(s3 - mx);
    float sm = e0 + e1 + e2 + e3;
    sm += __shfl_xor(sm, 16);
    sm += __shfl_xor(sm, 32);
    float inv = 1.0f / sm;
    bf16x4 pk;
    pk[0] = (__bf16)(e0 * inv); pk[1] = (__bf16)(e1 * inv);
    pk[2] = (__bf16)(e2 * inv); pk[3] = (__bf16)(e3 * inv);
    *(bf16x4*)(Ps + wid * 512 + mrow * 32 + kgrp * 4) = pk;
    // A-frag: probs[i=mrow][j = kgrp*8..+7] (zeros for j>=16, zeroed in A0)
    bf16x8 pf = *(const bf16x8*)(Ps + wid * 512 + mrow * 32 + kgrp * 8);
#pragma unroll
    for (int dt = 0; dt < 2; ++dt) {
      int c = head * 32 + dt * 16 + mrow;
      // B-frag: v[j][d=mrow] for 8 consecutive j. Reads for j>=16 land in
      // Vs padding cols / Ps, which are ZEROED (Phase A0) -> 0*0=0, finite.
      bf16x4 va = *(const bf16x4*)(Vs + c * 72 + kgrp * 32 + win * 4);
      bf16x4 vb = *(const bf16x4*)(Vs + c * 72 + kgrp * 32 + 16 + win * 4);
      bf16x8 vf;
#pragma unroll
      for (int t = 0; t < 4; ++t) { vf[t] = va[t]; vf[4 + t] = vb[t]; }
      f32x4 o = __builtin_amdgcn_mfma_f32_16x16x32_bf16(pf, vf, z4, 0, 0, 0);
      bf16x4 ok;
#pragma unroll
      for (int t = 0; t < 4; ++t) ok[t] = (__bf16)o[t];
      osav[u][dt] = ok;
    }
  }
  __syncthreads();   // all QKs reads done -> safe to overwrite with Os
#pragma unroll
  for (int u = 0; u < 4; ++u) {
    int wh = wid * 4 + u, win = wh >> 3, head = wh & 7;
#pragma unroll
    for (int dt = 0; dt < 2; ++dt) {
      int c = head * 32 + dt * 16 + mrow;
      *(bf16x4*)(Os + c * 72 + kgrp * 16 + win * 4) = osav[u][dt];
    }
  }
  __syncthreads();

  // ---- writeout: attn_img from Os, v_img from Vs (coalesced 16B) ----
#pragma unroll
  for (int it = 0; it < 4; ++it) {
    int idx = tid + it * 512;            // 2048 = c(256) x seg(8)
    int c = idx >> 3, seg = idx & 7;
    bf16x8 o8 = *(const bf16x8*)(Os + c * 72 + seg * 8);
    bf16x8 v8 = *(const bf16x8*)(Vs + c * 72 + seg * 8);
    size_t g = ((size_t)(b * 256 + c) * 256 + h0 + (seg >> 1)) * 256 + w0 + (seg & 1) * 8;
    *(bf16x8*)(attn_img + g) = o8;
    *(bf16x8*)(v_img + g) = v8;
  }
}

// ------------------------------------------------------------ pw GEMM -------
// Block 256 thr (4 waves), tile = 64 contiguous w of one row, all 256 o.
// R1: double-bounce transpose staging (conflict-free), K-chunked 2x128
// (LDS 35.8KB -> 4 blocks/CU), swapped-operand MFMA -> D[px][o] -> bf16x4
// vector epilogue stores.
__global__ __launch_bounds__(256, 4) void k_pw(
    const __bf16* __restrict__ vimg, const __bf16* __restrict__ Wpw,
    __bf16* __restrict__ vg)
{
  __shared__ __bf16 Ns[128 * 72];       // natural [c_local][px]
  __shared__ __bf16 Xs[64 * 136];       // transposed [px][c_local]
  const int tid = threadIdx.x, lane = tid & 63, wid = tid >> 6;
  const int mrow = lane & 15, kgrp = lane >> 4;
  const int b = blockIdx.z, h = blockIdx.y, w0 = blockIdx.x * 64;
  const size_t rowbase = ((size_t)(b * 256) * 256 + h) * 256 + w0;

  f32x4 acc[2][2][4];
#pragma unroll
  for (int oh = 0; oh < 2; ++oh)
#pragma unroll
    for (int mt = 0; mt < 2; ++mt)
#pragma unroll
      for (int nt = 0; nt < 4; ++nt) acc[oh][mt][nt] = (f32x4){0.f, 0.f, 0.f, 0.f};

  for (int kc = 0; kc < 2; ++kc) {
    // stage global -> Ns (128 c x 64 px), vectorized, conflict-free
#pragma unroll
    for (int it = 0; it < 4; ++it) {
      int idx = it * 256 + tid;          // c_local(128) x g(8)
      int cl = idx >> 3, g = idx & 7;
      bf16x8 v = *(const bf16x8*)(vimg + rowbase + (size_t)(kc * 128 + cl) * HW + g * 8);
      *(bf16x8*)(Ns + cl * 72 + g * 8) = v;
    }
    __syncthreads();
    // bounce Ns -> Xs: lanes span 64 consecutive px (2-way reads, free),
    // then one vectorized bf16x8 write per 8-channel octet.
#pragma unroll
    for (int it = 0; it < 4; ++it) {
      int task = it * 256 + tid;         // px(64) x oct(16)
      int px = task & 63, oct = task >> 6;
      int c0 = oct * 8;
      bf16x8 r;
#pragma unroll
      for (int j = 0; j < 8; ++j) r[j] = Ns[(c0 + j) * 72 + px];
      *(bf16x8*)(Xs + px * 136 + c0) = r;
    }
    __syncthreads();
    // MFMA over this k-chunk (operands swapped: D[px][o])
#pragma unroll
    for (int oh = 0; oh < 2; ++oh) {
      const int o0 = oh * 128 + wid * 32;
#pragma unroll
      for (int ks = 0; ks < 4; ++ks) {
        bf16x8 af[2], bm[4];
#pragma unroll
        for (int mt = 0; mt < 2; ++mt)
          af[mt] = *(const bf16x8*)(Wpw + (size_t)(o0 + mt * 16 + mrow) * 256 + kc * 128 + ks * 32 + kgrp * 8);
#pragma unroll
        for (int nt = 0; nt < 4; ++nt)
          bm[nt] = *(const bf16x8*)(Xs + (nt * 16 + mrow) * 136 + ks * 32 + kgrp * 8);
#pragma unroll
        for (int mt = 0; mt < 2; ++mt)
#pragma unroll
          for (int nt = 0; nt < 4; ++nt)
            acc[oh][mt][nt] = __builtin_amdgcn_mfma_f32_16x16x32_bf16(bm[nt], af[mt], acc[oh][mt][nt], 0, 0, 0);
      }
    }
    __syncthreads();   // Xs/Ns reuse safe for next chunk
  }
  // epilogue: lane holds D[px = nt*16 + kgrp*4 + t][o = o0 + mt*16 + mrow]
#pragma unroll
  for (int oh = 0; oh < 2; ++oh) {
#pragma unroll
    for (int mt = 0; mt < 2; ++mt) {
      int o = oh * 128 + wid * 32 + mt * 16 + mrow;
#pragma unroll
      for (int nt = 0; nt < 4; ++nt) {
        bf16x4 pk;
#pragma unroll
        for (int t = 0; t < 4; ++t) pk[t] = (__bf16)acc[oh][mt][nt][t];
        *(bf16x4*)(vg + rowbase + (size_t)o * HW + nt * 16 + kgrp * 4) = pk;
      }
    }
  }
}

// ------------------------------------------------------------- mix ----------
// t = v_img + (dw3x3(vg)*s_g + bias_g) + ax + ay
// ax[h] = (A~[h-1]+A~[h]+A~[h+1]+A~[h+2])/4, A~[256]=A[254], A~[-1]=A~[257]=0
// ay analogous along w.
__global__ __launch_bounds__(256, 4) void k_mix(
    const __bf16* __restrict__ vg, const __bf16* __restrict__ attn,
    const __bf16* __restrict__ vimg, const float* __restrict__ dwf,
    const float* __restrict__ bias_g, __bf16* __restrict__ tout)
{
  __shared__ __bf16 VgS[18 * 256];
  __shared__ __bf16 AtS[19 * 256];
  __shared__ __bf16 ViS[16 * 256];
  const int tid = threadIdx.x;
  const int b = blockIdx.z, c = blockIdx.y, h0 = blockIdx.x * 16;
  const size_t plane = (size_t)(b * 256 + c) * HW;

  for (int idx = tid; idx < 576; idx += 256) {        // vg rows h0-1..h0+16
    int row = idx >> 5, g = idx & 31;
    int hg = h0 - 1 + row;
    bf16x8 v;
#pragma unroll
    for (int j = 0; j < 8; ++j) v[j] = (__bf16)0.f;
    if (hg >= 0 && hg < 256)
      v = *(const bf16x8*)(vg + plane + (size_t)hg * 256 + g * 8);
    *(bf16x8*)(VgS + row * 256 + g * 8) = v;
  }
  for (int idx = tid; idx < 608; idx += 256) {        // attn rows h0-1..h0+17
    int row = idx >> 5, g = idx & 31;
    int hg = h0 - 1 + row;
    bf16x8 v;
#pragma unroll
    for (int j = 0; j < 8; ++j) v[j] = (__bf16)0.f;
    if (hg >= 0 && hg <= 256) {
      int hs = (hg == 256) ? 254 : hg;                // reflect-appended row
      v = *(const bf16x8*)(attn + plane + (size_t)hs * 256 + g * 8);
    }
    *(bf16x8*)(AtS + row * 256 + g * 8) = v;
  }
  for (int idx = tid; idx < 512; idx += 256) {        // v_img rows h0..h0+15
    int row = idx >> 5, g = idx & 31;
    *(bf16x8*)(ViS + row * 256 + g * 8) =
        *(const bf16x8*)(vimg + plane + (size_t)(h0 + row) * 256 + g * 8);
  }
  float kw[9];
#pragma unroll
  for (int i = 0; i < 9; ++i) kw[i] = dwf[c * 9 + i];
  const float bg = bias_g[c];
  __syncthreads();

  const int hl = tid >> 4, wb = (tid & 15) * 16;
  const __bf16* v0 = VgS + hl * 256;
  const __bf16* v1 = v0 + 256;
  const __bf16* v2 = v1 + 256;
  const __bf16* a0 = AtS + hl * 256;
  const __bf16* a1 = a0 + 256;
  const __bf16* a2 = a1 + 256;
  const __bf16* a3 = a2 + 256;
  const __bf16* vi = ViS + hl * 256;
  const size_t orow = plane + (size_t)(h0 + hl) * 256;
  for (int w8 = 0; w8 < 2; ++w8) {
    bf16x8 res;
#pragma unroll
    for (int j = 0; j < 8; ++j) {
      int w = wb + w8 * 8 + j;
      int xm = w - 1, xp = w + 1;
      float conv = kw[1] * (float)v0[w] + kw[4] * (float)v1[w] + kw[7] * (float)v2[w];
      if (xm >= 0)
        conv += kw[0] * (float)v0[xm] + kw[3] * (float)v1[xm] + kw[6] * (float)v2[xm];
      if (xp < 256)
        conv += kw[2] * (float)v0[xp] + kw[5] * (float)v1[xp] + kw[8] * (float)v2[xp];
      float ax = 0.25f * ((float)a0[w] + (float)a1[w] + (float)a2[w] + (float)a3[w]);
      float aym = (w >= 1) ? (float)a1[w - 1] : 0.f;
      float ay1 = (w + 1 <= 255) ? (float)a1[w + 1] : (float)a1[254];
      float ay2;
      int x2 = w + 2;
      if (x2 <= 255) ay2 = (float)a1[x2];
      else if (x2 == 256) ay2 = (float)a1[254];
      else ay2 = 0.f;
      float ay = 0.25f * (aym + (float)a1[w] + ay1 + ay2);
      res[j] = (__bf16)((float)vi[w] + conv + bg + ax + ay);
    }
    *(bf16x8*)(tout + orow + wb + w8 * 8) = res;
  }
}

// ------------------------------------------------------------ proj GEMM -----
// Same structure as k_pw; fp32 output with folded-BN bias, direct f32x4
// vector stores (no precision loss vs R0: acc stays fp32 end-to-end).
__global__ __launch_bounds__(256, 4) void k_proj(
    const __bf16* __restrict__ tin, const __bf16* __restrict__ Wp,
    const float* __restrict__ bias_p, float* __restrict__ out)
{
  __shared__ __bf16 Ns[128 * 72];
  __shared__ __bf16 Xs[64 * 136];
  const int tid = threadIdx.x, lane = tid & 63, wid = tid >> 6;
  const int mrow = lane & 15, kgrp = lane >> 4;
  const int b = blockIdx.z, h = blockIdx.y, w0 = blockIdx.x * 64;
  const size_t rowbase = ((size_t)(b * 256) * 256 + h) * 256 + w0;

  f32x4 acc[2][2][4];
#pragma unroll
  for (int oh = 0; oh < 2; ++oh)
#pragma unroll
    for (int mt = 0; mt < 2; ++mt)
#pragma unroll
      for (int nt = 0; nt < 4; ++nt) acc[oh][mt][nt] = (f32x4){0.f, 0.f, 0.f, 0.f};

  for (int kc = 0; kc < 2; ++kc) {
#pragma unroll
    for (int it = 0; it < 4; ++it) {
      int idx = it * 256 + tid;
      int cl = idx >> 3, g = idx & 7;
      bf16x8 v = *(const bf16x8*)(tin + rowbase + (size_t)(kc * 128 + cl) * HW + g * 8);
      *(bf16x8*)(Ns + cl * 72 + g * 8) = v;
    }
    __syncthreads();
#pragma unroll
    for (int it = 0; it < 4; ++it) {
      int task = it * 256 + tid;
      int px = task & 63, oct = task >> 6;
      int c0 = oct * 8;
      bf16x8 r;
#pragma unroll
      for (int j = 0; j < 8; ++j) r[j] = Ns[(c0 + j) * 72 + px];
      *(bf16x8*)(Xs + px * 136 + c0) = r;
    }
    __syncthreads();
#pragma unroll
    for (int oh = 0; oh < 2; ++oh) {
      const int o0 = oh * 128 + wid * 32;
#pragma unroll
      for (int ks = 0; ks < 4; ++ks) {
        bf16x8 af[2], bm[4];
#pragma unroll
        for (int mt = 0; mt < 2; ++mt)
          af[mt] = *(const bf16x8*)(Wp + (size_t)(o0 + mt * 16 + mrow) * 256 + kc * 128 + ks * 32 + kgrp * 8);
#pragma unroll
        for (int nt = 0; nt < 4; ++nt)
          bm[nt] = *(const bf16x8*)(Xs + (nt * 16 + mrow) * 136 + ks * 32 + kgrp * 8);
#pragma unroll
        for (int mt = 0; mt < 2; ++mt)
#pragma unroll
          for (int nt = 0; nt < 4; ++nt)
            acc[oh][mt][nt] = __builtin_amdgcn_mfma_f32_16x16x32_bf16(bm[nt], af[mt], acc[oh][mt][nt], 0, 0, 0);
      }
    }
    __syncthreads();
  }
#pragma unroll
  for (int oh = 0; oh < 2; ++oh) {
#pragma unroll
    for (int mt = 0; mt < 2; ++mt) {
      int o = oh * 128 + wid * 32 + mt * 16 + mrow;
      float bb = bias_p[o];
#pragma unroll
      for (int nt = 0; nt < 4; ++nt) {
        f32x4 r;
#pragma unroll
        for (int t = 0; t < 4; ++t) r[t] = acc[oh][mt][nt][t] + bb;
        *(f32x4*)(out + rowbase + (size_t)o * HW + nt * 16 + kgrp * 4) = r;
      }
    }
  }
}

// ----------------------------------------------------------- launcher -------
extern "C" void kernel_launch(void* const* d_in, const int* in_sizes, int n_in,
                              void* d_out, int out_size, void* d_ws, size_t ws_size,
                              hipStream_t stream) {
  const float* x      = (const float*)d_in[0];
  const float* qkv_w  = (const float*)d_in[1];
  const float* qkv_b  = (const float*)d_in[2];
  const float* rel    = (const float*)d_in[3];
  const float* gpw    = (const float*)d_in[4];
  const float* gdw    = (const float*)d_in[5];
  const float* gg     = (const float*)d_in[6];
  const float* gb     = (const float*)d_in[7];
  const float* gm     = (const float*)d_in[8];
  const float* gv     = (const float*)d_in[9];
  const float* pw     = (const float*)d_in[10];
  const float* pg     = (const float*)d_in[11];
  const float* pb     = (const float*)d_in[12];
  const float* pm     = (const float*)d_in[13];
  const float* pv     = (const float*)d_in[14];

  char* ws = (char*)d_ws;
  __bf16* Wqkv   = (__bf16*)(ws + 0);
  __bf16* Wpw    = (__bf16*)(ws + 393216);
  __bf16* Wproj  = (__bf16*)(ws + 524288);
  float*  bqkv   = (float*)(ws + 655360);
  float*  biasT  = (float*)(ws + 658432);
  float*  dwf    = (float*)(ws + 666624);
  float*  bias_g = (float*)(ws + 675840);
  float*  bias_p = (float*)(ws + 676864);
  __bf16* attn_img = (__bf16*)(ws + (1 << 20));
  __bf16* v_img    = attn_img + 67108864;
  __bf16* vg       = v_img + 67108864;
  __bf16* tbuf     = vg + 67108864;
  float* out = (float*)d_out;

  // allow 145KB dynamic LDS on gfx950 (ignore failure; harmless if no-op)
  (void)hipFuncSetAttribute((const void*)k_qkv_attn,
                            hipFuncAttributeMaxDynamicSharedMemorySize, K2_SMEM);

  k_prep<<<1302, 256, 0, stream>>>(qkv_w, qkv_b, rel, gpw, gdw, gg, gb, gm, gv,
                                   pw, pg, pb, pm, pv,
                                   Wqkv, Wpw, Wproj, bqkv, biasT, dwf, bias_g, bias_p);

  dim3 g2(16, 64, 4);
  k_qkv_attn<<<g2, 512, K2_SMEM, stream>>>(x, Wqkv, bqkv, biasT, attn_img, v_img);

  dim3 g3(4, 256, 4);
  k_pw<<<g3, 256, 0, stream>>>(v_img, Wpw, vg);

  dim3 g4(16, 256, 4);
  k_mix<<<g4, 256, 0, stream>>>(vg, attn_img, v_img, dwf, bias_g, tbuf);

  k_proj<<<g3, 256, 0, stream>>>(tbuf, Wproj, bias_p, out);
}